// Round 14
// baseline (240.579 us; speedup 1.0000x reference)
//
#include <hip/hip_runtime.h>

using u16 = unsigned short;
using u32 = unsigned int;
using short8 = __attribute__((ext_vector_type(8))) short;
using f32x4  = __attribute__((ext_vector_type(4))) float;

static inline int cdiv(long long a, long long b) { return (int)((a + b - 1) / b); }

__device__ __forceinline__ u16 f2bf(float x) {
    u32 u = __builtin_bit_cast(u32, x);
    u += 0x7fffu + ((u >> 16) & 1u);   // RTNE
    return (u16)(u >> 16);
}
__device__ __forceinline__ float bf2f(u16 h) {
    u32 u = ((u32)h) << 16;
    return __builtin_bit_cast(float, u);
}
__device__ __forceinline__ float bflo(u32 v) {
    return __builtin_bit_cast(float, v << 16);
}
__device__ __forceinline__ float bfhi(u32 v) {
    return __builtin_bit_cast(float, v & 0xffff0000u);
}

// ===========================================================================
// CSR build, 2-level counting sort. Bucket = 1024 destination nodes.
// Staging word: (c & 1023) << 17 | r   -- requires N < 131072.
#define BKT_SH 10
#define BKT_MASK ((1 << BKT_SH) - 1)
#define HCHUNK 8192     // k_init histogram chunk
#define CHUNK 4096      // passA chunk

// Fused: [blocks 0..NBH) edge-bucket histogram -> bpart (non-atomic partials,
// no pre-zero needed); [blocks NBH..) transposed bf16 weight panel prep.
__global__ __launch_bounds__(256) void k_init(const int* __restrict__ ei,
                                              int* __restrict__ bpart, int E, int NBH,
                                              const float* __restrict__ Wego,
                                              const float* __restrict__ Wconv,
                                              const float* __restrict__ Wcls,
                                              u16* __restrict__ WTin,
                                              u16* __restrict__ WT1,
                                              u16* __restrict__ WcatT) {
    if ((int)blockIdx.x < NBH) {
        __shared__ int lb[128];
        if (threadIdx.x < 128) lb[threadIdx.x] = 0;
        __syncthreads();
        const int eb = blockIdx.x * HCHUNK;
#pragma unroll
        for (int k = 0; k < 32; ++k) {
            int e = eb + k * 256 + threadIdx.x;
            if (e < E) atomicAdd(&lb[ei[E + e] >> BKT_SH], 1);
        }
        __syncthreads();
        if (threadIdx.x < 128)
            bpart[blockIdx.x * 128 + threadIdx.x] = lb[threadIdx.x];
    } else {
        int t = ((int)blockIdx.x - NBH) * 256 + threadIdx.x;
        if (t < 128 * 64) {
            int seg = t >> 6, d = t & 63;
            float v = (seg < 64) ? Wconv[d * 64 + seg] : Wego[d * 64 + (seg - 64)];
            WTin[t] = f2bf(v);
        } else if (t < 128 * 64 + 64 * 64) {
            int u = t - 128 * 64;
            int c = u >> 6, d = u & 63;
            WT1[u] = f2bf(Wconv[64 * 64 + d * 64 + c]);
        } else if (t < 128 * 64 + 64 * 64 + 48 * 192) {
            int u = t - (128 * 64 + 64 * 64);
            int c = u / 192, d = u - c * 192;
            WcatT[u] = f2bf(c < 40 ? Wcls[d * 40 + c] : 0.f);
        }
    }
}

// Parallel reduce of bpart (8 slices x 128 buckets, coalesced) + exclusive scan.
__global__ __launch_bounds__(1024) void k_bscan(const int* __restrict__ bpart, int NBH,
                                                int* __restrict__ bbase,
                                                int* __restrict__ bcursor, int NB) {
    __shared__ int part[8][128];
    __shared__ int s[128];
    const int t = threadIdx.x;
    const int bucket = t & 127, slice = t >> 7;
    int c = 0;
    for (int b = slice; b < NBH; b += 8) c += bpart[b * 128 + bucket];
    part[slice][bucket] = c;
    __syncthreads();
    int v = 0;
    if (t < 128) {
#pragma unroll
        for (int k = 0; k < 8; ++k) v += part[k][t];
        if (t >= NB) v = 0;
        s[t] = v;
    }
    __syncthreads();
    for (int st = 1; st < 128; st <<= 1) {
        int add = (t >= st && t < 128) ? s[t - st] : 0;
        __syncthreads();
        if (t < 128) s[t] += add;
        __syncthreads();
    }
    if (t < NB) {
        int excl = s[t] - v;
        bbase[t] = excl;
        bcursor[t] = excl;
        if (t == NB - 1) bbase[NB] = s[t];   // == E
    }
}

__global__ __launch_bounds__(256) void k_passA(const int* __restrict__ ei,
                                               int* __restrict__ bcursor,
                                               u32* __restrict__ sta, int E) {
    __shared__ int lcnt[128];
    __shared__ int lcur[128];
    if (threadIdx.x < 128) lcnt[threadIdx.x] = 0;
    __syncthreads();
    const int eb = blockIdx.x * CHUNK;
    int er[16], ec[16];
#pragma unroll
    for (int k = 0; k < 16; ++k) {
        int e = eb + k * 256 + threadIdx.x;
        if (e < E) {
            er[k] = ei[e];
            ec[k] = ei[E + e];
            atomicAdd(&lcnt[ec[k] >> BKT_SH], 1);
        } else {
            ec[k] = -1;
        }
    }
    __syncthreads();
    if (threadIdx.x < 128)
        lcur[threadIdx.x] = lcnt[threadIdx.x] > 0
                          ? atomicAdd(&bcursor[threadIdx.x], lcnt[threadIdx.x]) : 0;
    __syncthreads();
#pragma unroll
    for (int k = 0; k < 16; ++k) {
        if (ec[k] >= 0) {
            int pos = atomicAdd(&lcur[ec[k] >> BKT_SH], 1);
            sta[pos] = ((u32)(ec[k] & BKT_MASK) << 17) | (u32)er[k];
        }
    }
}

__global__ __launch_bounds__(256) void k_passB(const u32* __restrict__ sta,
                                               const int* __restrict__ bbase,
                                               int* __restrict__ indptr,
                                               float* __restrict__ dis,
                                               int* __restrict__ rows,
                                               int N, int NB) {
    __shared__ int lcnt[1024];
    __shared__ int cur[1024];
    __shared__ int ps[256];
    const int b = blockIdx.x;
    const int t = threadIdx.x;
    const int base = b << BKT_SH;
    const int e0 = bbase[b], e1 = bbase[b + 1];

#pragma unroll
    for (int k = 0; k < 4; ++k) lcnt[k * 256 + t] = 0;
    __syncthreads();
    for (int e = e0 + t; e < e1; e += 256)
        atomicAdd(&lcnt[sta[e] >> 17], 1);
    __syncthreads();

    int a0 = lcnt[t * 4 + 0], a1 = lcnt[t * 4 + 1];
    int a2 = lcnt[t * 4 + 2], a3 = lcnt[t * 4 + 3];
    int sum = a0 + a1 + a2 + a3;
    ps[t] = sum;
    __syncthreads();
    for (int st = 1; st < 256; st <<= 1) {
        int add = (t >= st) ? ps[t - st] : 0;
        __syncthreads();
        ps[t] += add;
        __syncthreads();
    }
    int ex = e0 + ps[t] - sum;
    int exs[4] = {ex, ex + a0, ex + a0 + a1, ex + a0 + a1 + a2};
    int cnts[4] = {a0, a1, a2, a3};
#pragma unroll
    for (int k = 0; k < 4; ++k) {
        int j = t * 4 + k;
        cur[j] = exs[k];
        int node = base + j;
        if (node < N) {
            indptr[node] = exs[k];
            dis[node] = rsqrtf((float)cnts[k] + 1.0f);   // self-loop adds 1
        }
    }
    if (b == NB - 1 && t == 0) indptr[N] = bbase[NB];    // == E
    __syncthreads();

    for (int e = e0 + t; e < e1; e += 256) {
        u32 v = sta[e];
        int pos = atomicAdd(&cur[v >> 17], 1);
        rows[pos] = (int)(v & 0x1FFFF);
    }
}

// ===========================================================================
// Fused cast + input layer (MFMA).
// cols 0..63  -> hws1 SLICED [s][N][8] (bf16, dis-scaled)  [= dis * x@Wconv0]
// cols 64..127-> hall[:,0:64] (relu+bego)                  [= P0] (stride 192)
__global__ __launch_bounds__(256) void k_in(const float* __restrict__ x,
                                            const u16* __restrict__ WTin,
                                            const float* __restrict__ dis,
                                            const float* __restrict__ bego,
                                            u16* __restrict__ hws1,
                                            u16* __restrict__ hall, int N) {
    const int wid = (blockIdx.x * 256 + threadIdx.x) >> 6;
    const int l = threadIdx.x & 63;
    if (wid * 16 >= N) return;
    const int lr = l & 15;
    const int lk = l >> 4;

    int r_ld = wid * 16 + lr;
    if (r_ld >= N) r_ld = N - 1;
    const float* xrow = x + (size_t)r_ld * 64 + lk * 8;
    float4 u0 = *(const float4*)(xrow);
    float4 u1 = *(const float4*)(xrow + 4);
    float4 u2 = *(const float4*)(xrow + 32);
    float4 u3 = *(const float4*)(xrow + 36);
    short8 a0, a1;
    a0[0] = (short)f2bf(u0.x); a0[1] = (short)f2bf(u0.y);
    a0[2] = (short)f2bf(u0.z); a0[3] = (short)f2bf(u0.w);
    a0[4] = (short)f2bf(u1.x); a0[5] = (short)f2bf(u1.y);
    a0[6] = (short)f2bf(u1.z); a0[7] = (short)f2bf(u1.w);
    a1[0] = (short)f2bf(u2.x); a1[1] = (short)f2bf(u2.y);
    a1[2] = (short)f2bf(u2.z); a1[3] = (short)f2bf(u2.w);
    a1[4] = (short)f2bf(u3.x); a1[5] = (short)f2bf(u3.y);
    a1[6] = (short)f2bf(u3.z); a1[7] = (short)f2bf(u3.w);

    float dvals[4];
#pragma unroll
    for (int rg = 0; rg < 4; ++rg) {
        int r = wid * 16 + lk * 4 + rg;
        dvals[rg] = dis[r < N ? r : N - 1];
    }

    for (int ct = 0; ct < 8; ++ct) {
        const u16* wrow = WTin + ((size_t)(ct * 16 + lr)) * 64 + lk * 8;
        short8 b0 = *(const short8*)wrow;
        short8 b1 = *(const short8*)(wrow + 32);
        f32x4 acc = {0.f, 0.f, 0.f, 0.f};
        acc = __builtin_amdgcn_mfma_f32_16x16x32_bf16(a0, b0, acc, 0, 0, 0);
        acc = __builtin_amdgcn_mfma_f32_16x16x32_bf16(a1, b1, acc, 0, 0, 0);
        const int col = ct * 16 + lr;
        if (col < 64) {
            const size_t sbase = (size_t)(col >> 3) * N * 8 + (col & 7);
#pragma unroll
            for (int rg = 0; rg < 4; ++rg) {
                int r = wid * 16 + lk * 4 + rg;
                if (r < N) hws1[sbase + (size_t)r * 8] = f2bf(dvals[rg] * acc[rg]);
            }
        } else {
            float be = bego[col - 64];
#pragma unroll
            for (int rg = 0; rg < 4; ++rg) {
                int r = wid * 16 + lk * 4 + rg;
                if (r < N) hall[(size_t)r * 192 + (col - 64)] = f2bf(fmaxf(acc[rg] + be, 0.f));
            }
        }
    }
}

// ===========================================================================
// Gather v3: XCD feature-sharded. slice s = blockIdx & 7 -> lands on XCD s
// (round-robin dispatch); hws_in is [8][N][8] so slice s touches only its
// own contiguous N*16B = 1.6 MB region -> L2-resident per XCD.
// 4 lanes per node (lane c = u32 feature-pair), 64 nodes per 256-thr block.
__global__ __launch_bounds__(256) void k_gather(const int* __restrict__ indptr,
                                                const int* __restrict__ rows,
                                                const float* __restrict__ dis,
                                                const float* __restrict__ bconv,
                                                const u16* __restrict__ hws_in,
                                                u16* __restrict__ hall_dst, int N) {
    const int s = blockIdx.x & 7;             // feature slice == XCD
    const int chunk = blockIdx.x >> 3;
    const int g = threadIdx.x >> 2;           // node within chunk (0..63)
    const int c = threadIdx.x & 3;            // u32 within slice (features s*8+2c,+1)
    const int i = chunk * 64 + g;
    if (i >= N) return;

    const u32* src = (const u32*)hws_in + (size_t)s * N * 4;   // slice base
    u32 sv = src[(size_t)i * 4 + c];          // self-loop term
    float a0 = bflo(sv), a1 = bfhi(sv);

    int p0 = indptr[i], p1 = indptr[i + 1];
    int p = p0;
    for (; p + 8 <= p1; p += 8) {
        int r0 = rows[p + 0], r1 = rows[p + 1], r2 = rows[p + 2], r3 = rows[p + 3];
        int r4 = rows[p + 4], r5 = rows[p + 5], r6 = rows[p + 6], r7 = rows[p + 7];
        u32 v0 = src[(size_t)r0 * 4 + c];
        u32 v1 = src[(size_t)r1 * 4 + c];
        u32 v2 = src[(size_t)r2 * 4 + c];
        u32 v3 = src[(size_t)r3 * 4 + c];
        u32 v4 = src[(size_t)r4 * 4 + c];
        u32 v5 = src[(size_t)r5 * 4 + c];
        u32 v6 = src[(size_t)r6 * 4 + c];
        u32 v7 = src[(size_t)r7 * 4 + c];
        a0 += ((bflo(v0) + bflo(v1)) + (bflo(v2) + bflo(v3))) +
              ((bflo(v4) + bflo(v5)) + (bflo(v6) + bflo(v7)));
        a1 += ((bfhi(v0) + bfhi(v1)) + (bfhi(v2) + bfhi(v3))) +
              ((bfhi(v4) + bfhi(v5)) + (bfhi(v6) + bfhi(v7)));
    }
    for (; p + 4 <= p1; p += 4) {
        int r0 = rows[p + 0], r1 = rows[p + 1], r2 = rows[p + 2], r3 = rows[p + 3];
        u32 v0 = src[(size_t)r0 * 4 + c];
        u32 v1 = src[(size_t)r1 * 4 + c];
        u32 v2 = src[(size_t)r2 * 4 + c];
        u32 v3 = src[(size_t)r3 * 4 + c];
        a0 += (bflo(v0) + bflo(v1)) + (bflo(v2) + bflo(v3));
        a1 += (bfhi(v0) + bfhi(v1)) + (bfhi(v2) + bfhi(v3));
    }
    for (; p < p1; ++p) {
        u32 v = src[(size_t)rows[p] * 4 + c];
        a0 += bflo(v);
        a1 += bfhi(v);
    }

    float dsi = dis[i];
    float2 bb = *(const float2*)(bconv + s * 8 + 2 * c);
    float h0 = fmaxf(fmaf(dsi, a0, bb.x), 0.0f);
    float h1 = fmaxf(fmaf(dsi, a1, bb.y), 0.0f);
    ((u32*)hall_dst)[(size_t)i * 96 + s * 4 + c] = (u32)f2bf(h0) | ((u32)f2bf(h1) << 16);
}

// ===========================================================================
// hws2 = bf16(dis * (h1 @ Wconv1)) in SLICED layout; h1 = hall[:,64:128].
__global__ __launch_bounds__(256) void k_next1(const u16* __restrict__ hall,
                                               const u16* __restrict__ WT1,
                                               const float* __restrict__ dis,
                                               u16* __restrict__ hws, int N) {
    const int wid = (blockIdx.x * 256 + threadIdx.x) >> 6;
    const int l = threadIdx.x & 63;
    if (wid * 16 >= N) return;
    const int lr = l & 15;
    const int lk = l >> 4;

    int r_ld = wid * 16 + lr;
    if (r_ld >= N) r_ld = N - 1;
    const u16* arow = hall + (size_t)r_ld * 192 + 64 + lk * 8;
    short8 a0 = *(const short8*)arow;
    short8 a1 = *(const short8*)(arow + 32);

    float dvals[4];
#pragma unroll
    for (int rg = 0; rg < 4; ++rg) {
        int r = wid * 16 + lk * 4 + rg;
        dvals[rg] = dis[r < N ? r : N - 1];
    }

    for (int ct = 0; ct < 4; ++ct) {
        const u16* wrow = WT1 + ((size_t)(ct * 16 + lr)) * 64 + lk * 8;
        short8 b0 = *(const short8*)wrow;
        short8 b1 = *(const short8*)(wrow + 32);
        f32x4 acc = {0.f, 0.f, 0.f, 0.f};
        acc = __builtin_amdgcn_mfma_f32_16x16x32_bf16(a0, b0, acc, 0, 0, 0);
        acc = __builtin_amdgcn_mfma_f32_16x16x32_bf16(a1, b1, acc, 0, 0, 0);
        const int col = ct * 16 + lr;
        const size_t sbase = (size_t)(col >> 3) * N * 8 + (col & 7);
#pragma unroll
        for (int rg = 0; rg < 4; ++rg) {
            int r = wid * 16 + lk * 4 + rg;
            if (r < N) hws[sbase + (size_t)r * 8] = f2bf(dvals[rg] * acc[rg]);
        }
    }
}

// ===========================================================================
// Final classifier: out = bcls + hall[N,192] @ Wcls[192,40]. Single write.
__global__ __launch_bounds__(256) void k_clsall(const u16* __restrict__ hall,
                                                const u16* __restrict__ WcatT,
                                                const float* __restrict__ bcls,
                                                float* __restrict__ out, int N) {
    const int wid = (blockIdx.x * 256 + threadIdx.x) >> 6;
    const int l = threadIdx.x & 63;
    if (wid * 16 >= N) return;
    const int lr = l & 15;
    const int lk = l >> 4;

    int r_ld = wid * 16 + lr;
    if (r_ld >= N) r_ld = N - 1;
    const u16* arow = hall + (size_t)r_ld * 192 + lk * 8;
    short8 a[6];
#pragma unroll
    for (int kt = 0; kt < 6; ++kt) a[kt] = *(const short8*)(arow + kt * 32);

    for (int ct = 0; ct < 3; ++ct) {
        const u16* brow = WcatT + ((size_t)(ct * 16 + lr)) * 192 + lk * 8;
        f32x4 acc = {0.f, 0.f, 0.f, 0.f};
#pragma unroll
        for (int kt = 0; kt < 6; ++kt) {
            short8 b = *(const short8*)(brow + kt * 32);
            acc = __builtin_amdgcn_mfma_f32_16x16x32_bf16(a[kt], b, acc, 0, 0, 0);
        }
        const int col = ct * 16 + lr;
        if (col < 40) {
            float bc = bcls[col];
#pragma unroll
            for (int rg = 0; rg < 4; ++rg) {
                int r = wid * 16 + lk * 4 + rg;
                if (r < N) out[(size_t)r * 40 + col] = bc + acc[rg];
            }
        }
    }
}

// ===========================================================================
extern "C" void kernel_launch(void* const* d_in, const int* in_sizes, int n_in,
                              void* d_out, int out_size, void* d_ws, size_t ws_size,
                              hipStream_t stream) {
    const float* x     = (const float*)d_in[0];
    const int*   ei    = (const int*)d_in[1];   // [2,E] int32
    const float* Wego  = (const float*)d_in[2];
    const float* bego  = (const float*)d_in[3];
    const float* Wconv = (const float*)d_in[4]; // [2,64,64]
    const float* bconv = (const float*)d_in[5]; // [2,64]
    const float* Wcls  = (const float*)d_in[6]; // [192,40]
    const float* bcls  = (const float*)d_in[7];
    float* out = (float*)d_out;

    const int N = in_sizes[0] / 64;
    const int E = in_sizes[1] / 2;
    const int NB   = cdiv(N, 1 << BKT_SH);      // buckets (98)
    const int NBH  = cdiv(E, HCHUNK);           // histogram blocks (153)
    const int NBA  = cdiv(E, CHUNK);            // passA blocks (306)

    // workspace layout (u16 units unless noted):
    //  hall u16[N*192]  (aliased early: sta u32[E], dead before k_in)
    //  hws1 u16[8][N][8] | hws2 u16[8][N][8] |
    //  WTin[128*64] | WT1[64*64] | WcatT[48*192] |
    //  dis f[N] | indptr i[N+1+pad] | bbase i[132] | bcursor i[128] |
    //  rows i[E] | bpart i[NBH*128]
    u16* hall  = (u16*)d_ws;
    u32* sta   = (u32*)d_ws;                    // alias, dead before k_in
    u16* hws1  = hall + (size_t)N * 192;
    u16* hws2  = hws1 + (size_t)N * 64;
    u16* WTin  = hws2 + (size_t)N * 64;
    u16* WT1   = WTin + 128 * 64;
    u16* WcatT = WT1 + 64 * 64;
    float* dis = (float*)(WcatT + 48 * 192);
    int* indptr  = (int*)(dis + N);
    int* bbase   = indptr + N + 64;
    int* bcursor = bbase + 132;
    int* rows    = bcursor + 128;
    int* bpart   = rows + E;

    // ---- CSR build + weight prep (no memset: bpart is non-atomic) ----
    const int PREP_BLOCKS = cdiv(128 * 64 + 64 * 64 + 48 * 192, 256);
    k_init<<<NBH + PREP_BLOCKS, 256, 0, stream>>>(ei, bpart, E, NBH,
                                                  Wego, Wconv, Wcls, WTin, WT1, WcatT);
    k_bscan<<<1, 1024, 0, stream>>>(bpart, NBH, bbase, bcursor, NB);
    k_passA<<<NBA, 256, 0, stream>>>(ei, bcursor, sta, E);
    k_passB<<<NB, 256, 0, stream>>>(sta, bbase, indptr, dis, rows, N, NB);

    // ---- input layer (fused cast, MFMA) ----
    k_in<<<cdiv(cdiv(N, 16), 4), 256, 0, stream>>>(x, WTin, dis, bego, hws1, hall, N);

    // ---- hop 1: sharded gather -> h1 (hall slice 1); hws2 = dis*(h1@Wconv1) ----
    k_gather<<<cdiv(N, 64) * 8, 256, 0, stream>>>(indptr, rows, dis, bconv,
                                                  hws1, hall + 64, N);
    k_next1<<<cdiv(cdiv(N, 16), 4), 256, 0, stream>>>(hall, WT1, dis, hws2, N);

    // ---- hop 2: sharded gather -> h2 (hall slice 2) ----
    k_gather<<<cdiv(N, 64) * 8, 256, 0, stream>>>(indptr, rows, dis, bconv + 64,
                                                  hws2, hall + 128, N);

    // ---- classifier: out = bcls + hall @ Wcls (single pass) ----
    k_clsall<<<cdiv(cdiv(N, 16), 4), 256, 0, stream>>>(hall, WcatT, bcls, out, N);
}

// Round 15
// 240.281 us; speedup vs baseline: 1.0012x; 1.0012x over previous
//
#include <hip/hip_runtime.h>

using u16 = unsigned short;
using u32 = unsigned int;
using short8 = __attribute__((ext_vector_type(8))) short;
using f32x4  = __attribute__((ext_vector_type(4))) float;

static inline int cdiv(long long a, long long b) { return (int)((a + b - 1) / b); }

__device__ __forceinline__ u16 f2bf(float x) {
    u32 u = __builtin_bit_cast(u32, x);
    u += 0x7fffu + ((u >> 16) & 1u);   // RTNE
    return (u16)(u >> 16);
}
__device__ __forceinline__ float bf2f(u16 h) {
    u32 u = ((u32)h) << 16;
    return __builtin_bit_cast(float, u);
}
__device__ __forceinline__ float bflo(u32 v) {
    return __builtin_bit_cast(float, v << 16);
}
__device__ __forceinline__ float bfhi(u32 v) {
    return __builtin_bit_cast(float, v & 0xffff0000u);
}

// ===========================================================================
// CSR build, 2-level counting sort. Bucket = 1024 destination nodes.
// Staging word: (c & 1023) << 17 | r   -- requires N < 131072.
#define BKT_SH 10
#define BKT_MASK ((1 << BKT_SH) - 1)
#define HCHUNK 8192     // k_init histogram chunk
#define CHUNK 4096      // passA chunk

// Fused: [blocks 0..NBH) edge-bucket histogram -> bpart (non-atomic partials,
// no pre-zero needed); [blocks NBH..) transposed bf16 weight panel prep.
__global__ __launch_bounds__(256) void k_init(const int* __restrict__ ei,
                                              int* __restrict__ bpart, int E, int NBH,
                                              const float* __restrict__ Wego,
                                              const float* __restrict__ Wconv,
                                              const float* __restrict__ Wcls,
                                              u16* __restrict__ WTin,
                                              u16* __restrict__ WT1,
                                              u16* __restrict__ WcatT) {
    if ((int)blockIdx.x < NBH) {
        __shared__ int lb[128];
        if (threadIdx.x < 128) lb[threadIdx.x] = 0;
        __syncthreads();
        const int eb = blockIdx.x * HCHUNK;
#pragma unroll
        for (int k = 0; k < 32; ++k) {
            int e = eb + k * 256 + threadIdx.x;
            if (e < E) atomicAdd(&lb[ei[E + e] >> BKT_SH], 1);
        }
        __syncthreads();
        if (threadIdx.x < 128)
            bpart[blockIdx.x * 128 + threadIdx.x] = lb[threadIdx.x];
    } else {
        int t = ((int)blockIdx.x - NBH) * 256 + threadIdx.x;
        if (t < 128 * 64) {
            int seg = t >> 6, d = t & 63;
            float v = (seg < 64) ? Wconv[d * 64 + seg] : Wego[d * 64 + (seg - 64)];
            WTin[t] = f2bf(v);
        } else if (t < 128 * 64 + 64 * 64) {
            int u = t - 128 * 64;
            int c = u >> 6, d = u & 63;
            WT1[u] = f2bf(Wconv[64 * 64 + d * 64 + c]);
        } else if (t < 128 * 64 + 64 * 64 + 48 * 192) {
            int u = t - (128 * 64 + 64 * 64);
            int c = u / 192, d = u - c * 192;
            WcatT[u] = f2bf(c < 40 ? Wcls[d * 40 + c] : 0.f);
        }
    }
}

// Parallel reduce of bpart (8 slices x 128 buckets, coalesced) + exclusive scan.
__global__ __launch_bounds__(1024) void k_bscan(const int* __restrict__ bpart, int NBH,
                                                int* __restrict__ bbase,
                                                int* __restrict__ bcursor, int NB) {
    __shared__ int part[8][128];
    __shared__ int s[128];
    const int t = threadIdx.x;
    const int bucket = t & 127, slice = t >> 7;
    int c = 0;
    for (int b = slice; b < NBH; b += 8) c += bpart[b * 128 + bucket];
    part[slice][bucket] = c;
    __syncthreads();
    int v = 0;
    if (t < 128) {
#pragma unroll
        for (int k = 0; k < 8; ++k) v += part[k][t];
        if (t >= NB) v = 0;
        s[t] = v;
    }
    __syncthreads();
    for (int st = 1; st < 128; st <<= 1) {
        int add = (t >= st && t < 128) ? s[t - st] : 0;
        __syncthreads();
        if (t < 128) s[t] += add;
        __syncthreads();
    }
    if (t < NB) {
        int excl = s[t] - v;
        bbase[t] = excl;
        bcursor[t] = excl;
        if (t == NB - 1) bbase[NB] = s[t];   // == E
    }
}

__global__ __launch_bounds__(256) void k_passA(const int* __restrict__ ei,
                                               int* __restrict__ bcursor,
                                               u32* __restrict__ sta, int E) {
    __shared__ int lcnt[128];
    __shared__ int lcur[128];
    if (threadIdx.x < 128) lcnt[threadIdx.x] = 0;
    __syncthreads();
    const int eb = blockIdx.x * CHUNK;
    int er[16], ec[16];
#pragma unroll
    for (int k = 0; k < 16; ++k) {
        int e = eb + k * 256 + threadIdx.x;
        if (e < E) {
            er[k] = ei[e];
            ec[k] = ei[E + e];
            atomicAdd(&lcnt[ec[k] >> BKT_SH], 1);
        } else {
            ec[k] = -1;
        }
    }
    __syncthreads();
    if (threadIdx.x < 128)
        lcur[threadIdx.x] = lcnt[threadIdx.x] > 0
                          ? atomicAdd(&bcursor[threadIdx.x], lcnt[threadIdx.x]) : 0;
    __syncthreads();
#pragma unroll
    for (int k = 0; k < 16; ++k) {
        if (ec[k] >= 0) {
            int pos = atomicAdd(&lcur[ec[k] >> BKT_SH], 1);
            sta[pos] = ((u32)(ec[k] & BKT_MASK) << 17) | (u32)er[k];
        }
    }
}

__global__ __launch_bounds__(256) void k_passB(const u32* __restrict__ sta,
                                               const int* __restrict__ bbase,
                                               int* __restrict__ indptr,
                                               float* __restrict__ dis,
                                               int* __restrict__ rows,
                                               int N, int NB) {
    __shared__ int lcnt[1024];
    __shared__ int cur[1024];
    __shared__ int ps[256];
    const int b = blockIdx.x;
    const int t = threadIdx.x;
    const int base = b << BKT_SH;
    const int e0 = bbase[b], e1 = bbase[b + 1];

#pragma unroll
    for (int k = 0; k < 4; ++k) lcnt[k * 256 + t] = 0;
    __syncthreads();
    for (int e = e0 + t; e < e1; e += 256)
        atomicAdd(&lcnt[sta[e] >> 17], 1);
    __syncthreads();

    int a0 = lcnt[t * 4 + 0], a1 = lcnt[t * 4 + 1];
    int a2 = lcnt[t * 4 + 2], a3 = lcnt[t * 4 + 3];
    int sum = a0 + a1 + a2 + a3;
    ps[t] = sum;
    __syncthreads();
    for (int st = 1; st < 256; st <<= 1) {
        int add = (t >= st) ? ps[t - st] : 0;
        __syncthreads();
        ps[t] += add;
        __syncthreads();
    }
    int ex = e0 + ps[t] - sum;
    int exs[4] = {ex, ex + a0, ex + a0 + a1, ex + a0 + a1 + a2};
    int cnts[4] = {a0, a1, a2, a3};
#pragma unroll
    for (int k = 0; k < 4; ++k) {
        int j = t * 4 + k;
        cur[j] = exs[k];
        int node = base + j;
        if (node < N) {
            indptr[node] = exs[k];
            dis[node] = rsqrtf((float)cnts[k] + 1.0f);   // self-loop adds 1
        }
    }
    if (b == NB - 1 && t == 0) indptr[N] = bbase[NB];    // == E
    __syncthreads();

    for (int e = e0 + t; e < e1; e += 256) {
        u32 v = sta[e];
        int pos = atomicAdd(&cur[v >> 17], 1);
        rows[pos] = (int)(v & 0x1FFFF);
    }
}

// ===========================================================================
// Fused cast + input layer (MFMA).
// cols 0..63  -> hws1 SLICED [s][N][8] (bf16, dis-scaled)  [= dis * x@Wconv0]
// cols 64..127-> hall[:,0:64] (relu+bego)                  [= P0] (stride 192)
__global__ __launch_bounds__(256) void k_in(const float* __restrict__ x,
                                            const u16* __restrict__ WTin,
                                            const float* __restrict__ dis,
                                            const float* __restrict__ bego,
                                            u16* __restrict__ hws1,
                                            u16* __restrict__ hall, int N) {
    const int wid = (blockIdx.x * 256 + threadIdx.x) >> 6;
    const int l = threadIdx.x & 63;
    if (wid * 16 >= N) return;
    const int lr = l & 15;
    const int lk = l >> 4;

    int r_ld = wid * 16 + lr;
    if (r_ld >= N) r_ld = N - 1;
    const float* xrow = x + (size_t)r_ld * 64 + lk * 8;
    float4 u0 = *(const float4*)(xrow);
    float4 u1 = *(const float4*)(xrow + 4);
    float4 u2 = *(const float4*)(xrow + 32);
    float4 u3 = *(const float4*)(xrow + 36);
    short8 a0, a1;
    a0[0] = (short)f2bf(u0.x); a0[1] = (short)f2bf(u0.y);
    a0[2] = (short)f2bf(u0.z); a0[3] = (short)f2bf(u0.w);
    a0[4] = (short)f2bf(u1.x); a0[5] = (short)f2bf(u1.y);
    a0[6] = (short)f2bf(u1.z); a0[7] = (short)f2bf(u1.w);
    a1[0] = (short)f2bf(u2.x); a1[1] = (short)f2bf(u2.y);
    a1[2] = (short)f2bf(u2.z); a1[3] = (short)f2bf(u2.w);
    a1[4] = (short)f2bf(u3.x); a1[5] = (short)f2bf(u3.y);
    a1[6] = (short)f2bf(u3.z); a1[7] = (short)f2bf(u3.w);

    float dvals[4];
#pragma unroll
    for (int rg = 0; rg < 4; ++rg) {
        int r = wid * 16 + lk * 4 + rg;
        dvals[rg] = dis[r < N ? r : N - 1];
    }

    for (int ct = 0; ct < 8; ++ct) {
        const u16* wrow = WTin + ((size_t)(ct * 16 + lr)) * 64 + lk * 8;
        short8 b0 = *(const short8*)wrow;
        short8 b1 = *(const short8*)(wrow + 32);
        f32x4 acc = {0.f, 0.f, 0.f, 0.f};
        acc = __builtin_amdgcn_mfma_f32_16x16x32_bf16(a0, b0, acc, 0, 0, 0);
        acc = __builtin_amdgcn_mfma_f32_16x16x32_bf16(a1, b1, acc, 0, 0, 0);
        const int col = ct * 16 + lr;
        if (col < 64) {
            const size_t sbase = (size_t)(col >> 3) * N * 8 + (col & 7);
#pragma unroll
            for (int rg = 0; rg < 4; ++rg) {
                int r = wid * 16 + lk * 4 + rg;
                if (r < N) hws1[sbase + (size_t)r * 8] = f2bf(dvals[rg] * acc[rg]);
            }
        } else {
            float be = bego[col - 64];
#pragma unroll
            for (int rg = 0; rg < 4; ++rg) {
                int r = wid * 16 + lk * 4 + rg;
                if (r < N) hall[(size_t)r * 192 + (col - 64)] = f2bf(fmaxf(acc[rg] + be, 0.f));
            }
        }
    }
}

// ===========================================================================
// Gather v3: XCD feature-sharded. slice s = blockIdx & 7 -> lands on XCD s
// (round-robin dispatch); hws_in is [8][N][8] so slice s touches only its
// own contiguous N*16B = 1.6 MB region -> L2-resident per XCD.
// 4 lanes per node (lane c = u32 feature-pair), 64 nodes per 256-thr block.
__global__ __launch_bounds__(256) void k_gather(const int* __restrict__ indptr,
                                                const int* __restrict__ rows,
                                                const float* __restrict__ dis,
                                                const float* __restrict__ bconv,
                                                const u16* __restrict__ hws_in,
                                                u16* __restrict__ hall_dst, int N) {
    const int s = blockIdx.x & 7;             // feature slice == XCD
    const int chunk = blockIdx.x >> 3;
    const int g = threadIdx.x >> 2;           // node within chunk (0..63)
    const int c = threadIdx.x & 3;            // u32 within slice (features s*8+2c,+1)
    const int i = chunk * 64 + g;
    if (i >= N) return;

    const u32* src = (const u32*)hws_in + (size_t)s * N * 4;   // slice base
    u32 sv = src[(size_t)i * 4 + c];          // self-loop term
    float a0 = bflo(sv), a1 = bfhi(sv);

    int p0 = indptr[i], p1 = indptr[i + 1];
    int p = p0;
    for (; p + 8 <= p1; p += 8) {
        int r0 = rows[p + 0], r1 = rows[p + 1], r2 = rows[p + 2], r3 = rows[p + 3];
        int r4 = rows[p + 4], r5 = rows[p + 5], r6 = rows[p + 6], r7 = rows[p + 7];
        u32 v0 = src[(size_t)r0 * 4 + c];
        u32 v1 = src[(size_t)r1 * 4 + c];
        u32 v2 = src[(size_t)r2 * 4 + c];
        u32 v3 = src[(size_t)r3 * 4 + c];
        u32 v4 = src[(size_t)r4 * 4 + c];
        u32 v5 = src[(size_t)r5 * 4 + c];
        u32 v6 = src[(size_t)r6 * 4 + c];
        u32 v7 = src[(size_t)r7 * 4 + c];
        a0 += ((bflo(v0) + bflo(v1)) + (bflo(v2) + bflo(v3))) +
              ((bflo(v4) + bflo(v5)) + (bflo(v6) + bflo(v7)));
        a1 += ((bfhi(v0) + bfhi(v1)) + (bfhi(v2) + bfhi(v3))) +
              ((bfhi(v4) + bfhi(v5)) + (bfhi(v6) + bfhi(v7)));
    }
    for (; p + 4 <= p1; p += 4) {
        int r0 = rows[p + 0], r1 = rows[p + 1], r2 = rows[p + 2], r3 = rows[p + 3];
        u32 v0 = src[(size_t)r0 * 4 + c];
        u32 v1 = src[(size_t)r1 * 4 + c];
        u32 v2 = src[(size_t)r2 * 4 + c];
        u32 v3 = src[(size_t)r3 * 4 + c];
        a0 += (bflo(v0) + bflo(v1)) + (bflo(v2) + bflo(v3));
        a1 += (bfhi(v0) + bfhi(v1)) + (bfhi(v2) + bfhi(v3));
    }
    for (; p < p1; ++p) {
        u32 v = src[(size_t)rows[p] * 4 + c];
        a0 += bflo(v);
        a1 += bfhi(v);
    }

    float dsi = dis[i];
    float2 bb = *(const float2*)(bconv + s * 8 + 2 * c);
    float h0 = fmaxf(fmaf(dsi, a0, bb.x), 0.0f);
    float h1 = fmaxf(fmaf(dsi, a1, bb.y), 0.0f);
    ((u32*)hall_dst)[(size_t)i * 96 + s * 4 + c] = (u32)f2bf(h0) | ((u32)f2bf(h1) << 16);
}

// ===========================================================================
// hws2 = bf16(dis * (h1 @ Wconv1)) in SLICED layout; h1 = hall[:,64:128].
__global__ __launch_bounds__(256) void k_next1(const u16* __restrict__ hall,
                                               const u16* __restrict__ WT1,
                                               const float* __restrict__ dis,
                                               u16* __restrict__ hws, int N) {
    const int wid = (blockIdx.x * 256 + threadIdx.x) >> 6;
    const int l = threadIdx.x & 63;
    if (wid * 16 >= N) return;
    const int lr = l & 15;
    const int lk = l >> 4;

    int r_ld = wid * 16 + lr;
    if (r_ld >= N) r_ld = N - 1;
    const u16* arow = hall + (size_t)r_ld * 192 + 64 + lk * 8;
    short8 a0 = *(const short8*)arow;
    short8 a1 = *(const short8*)(arow + 32);

    float dvals[4];
#pragma unroll
    for (int rg = 0; rg < 4; ++rg) {
        int r = wid * 16 + lk * 4 + rg;
        dvals[rg] = dis[r < N ? r : N - 1];
    }

    for (int ct = 0; ct < 4; ++ct) {
        const u16* wrow = WT1 + ((size_t)(ct * 16 + lr)) * 64 + lk * 8;
        short8 b0 = *(const short8*)wrow;
        short8 b1 = *(const short8*)(wrow + 32);
        f32x4 acc = {0.f, 0.f, 0.f, 0.f};
        acc = __builtin_amdgcn_mfma_f32_16x16x32_bf16(a0, b0, acc, 0, 0, 0);
        acc = __builtin_amdgcn_mfma_f32_16x16x32_bf16(a1, b1, acc, 0, 0, 0);
        const int col = ct * 16 + lr;
        const size_t sbase = (size_t)(col >> 3) * N * 8 + (col & 7);
#pragma unroll
        for (int rg = 0; rg < 4; ++rg) {
            int r = wid * 16 + lk * 4 + rg;
            if (r < N) hws[sbase + (size_t)r * 8] = f2bf(dvals[rg] * acc[rg]);
        }
    }
}

// ===========================================================================
// Final classifier: out = bcls + hall[N,192] @ Wcls[192,40]. Single write.
__global__ __launch_bounds__(256) void k_clsall(const u16* __restrict__ hall,
                                                const u16* __restrict__ WcatT,
                                                const float* __restrict__ bcls,
                                                float* __restrict__ out, int N) {
    const int wid = (blockIdx.x * 256 + threadIdx.x) >> 6;
    const int l = threadIdx.x & 63;
    if (wid * 16 >= N) return;
    const int lr = l & 15;
    const int lk = l >> 4;

    int r_ld = wid * 16 + lr;
    if (r_ld >= N) r_ld = N - 1;
    const u16* arow = hall + (size_t)r_ld * 192 + lk * 8;
    short8 a[6];
#pragma unroll
    for (int kt = 0; kt < 6; ++kt) a[kt] = *(const short8*)(arow + kt * 32);

    for (int ct = 0; ct < 3; ++ct) {
        const u16* brow = WcatT + ((size_t)(ct * 16 + lr)) * 192 + lk * 8;
        f32x4 acc = {0.f, 0.f, 0.f, 0.f};
#pragma unroll
        for (int kt = 0; kt < 6; ++kt) {
            short8 b = *(const short8*)(brow + kt * 32);
            acc = __builtin_amdgcn_mfma_f32_16x16x32_bf16(a[kt], b, acc, 0, 0, 0);
        }
        const int col = ct * 16 + lr;
        if (col < 40) {
            float bc = bcls[col];
#pragma unroll
            for (int rg = 0; rg < 4; ++rg) {
                int r = wid * 16 + lk * 4 + rg;
                if (r < N) out[(size_t)r * 40 + col] = bc + acc[rg];
            }
        }
    }
}

// ===========================================================================
extern "C" void kernel_launch(void* const* d_in, const int* in_sizes, int n_in,
                              void* d_out, int out_size, void* d_ws, size_t ws_size,
                              hipStream_t stream) {
    const float* x     = (const float*)d_in[0];
    const int*   ei    = (const int*)d_in[1];   // [2,E] int32
    const float* Wego  = (const float*)d_in[2];
    const float* bego  = (const float*)d_in[3];
    const float* Wconv = (const float*)d_in[4]; // [2,64,64]
    const float* bconv = (const float*)d_in[5]; // [2,64]
    const float* Wcls  = (const float*)d_in[6]; // [192,40]
    const float* bcls  = (const float*)d_in[7];
    float* out = (float*)d_out;

    const int N = in_sizes[0] / 64;
    const int E = in_sizes[1] / 2;
    const int NB   = cdiv(N, 1 << BKT_SH);      // buckets (98)
    const int NBH  = cdiv(E, HCHUNK);           // histogram blocks (153)
    const int NBA  = cdiv(E, CHUNK);            // passA blocks (306)

    // workspace layout (u16 units unless noted):
    //  hall u16[N*192]  (aliased early: sta u32[E], dead before k_in)
    //  hws1 u16[8][N][8] | hws2 u16[8][N][8] |
    //  WTin[128*64] | WT1[64*64] | WcatT[48*192] |
    //  dis f[N] | indptr i[N+1+pad] | bbase i[132] | bcursor i[128] |
    //  rows i[E] | bpart i[NBH*128]
    u16* hall  = (u16*)d_ws;
    u32* sta   = (u32*)d_ws;                    // alias, dead before k_in
    u16* hws1  = hall + (size_t)N * 192;
    u16* hws2  = hws1 + (size_t)N * 64;
    u16* WTin  = hws2 + (size_t)N * 64;
    u16* WT1   = WTin + 128 * 64;
    u16* WcatT = WT1 + 64 * 64;
    float* dis = (float*)(WcatT + 48 * 192);
    int* indptr  = (int*)(dis + N);
    int* bbase   = indptr + N + 64;
    int* bcursor = bbase + 132;
    int* rows    = bcursor + 128;
    int* bpart   = rows + E;

    // ---- CSR build + weight prep (no memset: bpart is non-atomic) ----
    const int PREP_BLOCKS = cdiv(128 * 64 + 64 * 64 + 48 * 192, 256);
    k_init<<<NBH + PREP_BLOCKS, 256, 0, stream>>>(ei, bpart, E, NBH,
                                                  Wego, Wconv, Wcls, WTin, WT1, WcatT);
    k_bscan<<<1, 1024, 0, stream>>>(bpart, NBH, bbase, bcursor, NB);
    k_passA<<<NBA, 256, 0, stream>>>(ei, bcursor, sta, E);
    k_passB<<<NB, 256, 0, stream>>>(sta, bbase, indptr, dis, rows, N, NB);

    // ---- input layer (fused cast, MFMA) ----
    k_in<<<cdiv(cdiv(N, 16), 4), 256, 0, stream>>>(x, WTin, dis, bego, hws1, hall, N);

    // ---- hop 1: sharded gather -> h1 (hall slice 1); hws2 = dis*(h1@Wconv1) ----
    k_gather<<<cdiv(N, 64) * 8, 256, 0, stream>>>(indptr, rows, dis, bconv,
                                                  hws1, hall + 64, N);
    k_next1<<<cdiv(cdiv(N, 16), 4), 256, 0, stream>>>(hall, WT1, dis, hws2, N);

    // ---- hop 2: sharded gather -> h2 (hall slice 2) ----
    k_gather<<<cdiv(N, 64) * 8, 256, 0, stream>>>(indptr, rows, dis, bconv + 64,
                                                  hws2, hall + 128, N);

    // ---- classifier: out = bcls + hall @ Wcls (single pass) ----
    k_clsall<<<cdiv(cdiv(N, 16), 4), 256, 0, stream>>>(hall, WcatT, bcls, out, N);
}

// Round 16
// 186.937 us; speedup vs baseline: 1.2870x; 1.2854x over previous
//
#include <hip/hip_runtime.h>

using u16 = unsigned short;
using u32 = unsigned int;
using u64 = unsigned long long;
using short8 = __attribute__((ext_vector_type(8))) short;
using f32x4  = __attribute__((ext_vector_type(4))) float;

static inline int cdiv(long long a, long long b) { return (int)((a + b - 1) / b); }

__device__ __forceinline__ u16 f2bf(float x) {
    u32 u = __builtin_bit_cast(u32, x);
    u += 0x7fffu + ((u >> 16) & 1u);   // RTNE
    return (u16)(u >> 16);
}
__device__ __forceinline__ float bf2f(u16 h) {
    u32 u = ((u32)h) << 16;
    return __builtin_bit_cast(float, u);
}
__device__ __forceinline__ float bflo(u32 v) {
    return __builtin_bit_cast(float, v << 16);
}
__device__ __forceinline__ float bfhi(u32 v) {
    return __builtin_bit_cast(float, v & 0xffff0000u);
}

// ===========================================================================
// CSR build, 2-level counting sort. Bucket = 1024 destination nodes.
// Staging word: (c & 1023) << 17 | r   -- requires N < 131072.
#define BKT_SH 10
#define BKT_MASK ((1 << BKT_SH) - 1)
#define HCHUNK 8192     // k_init histogram chunk
#define CHUNK 4096      // passA chunk

// Fused: [blocks 0..NBH) edge-bucket histogram -> bpart (non-atomic partials,
// no pre-zero needed); [blocks NBH..) transposed bf16 weight panel prep.
__global__ __launch_bounds__(256) void k_init(const int* __restrict__ ei,
                                              int* __restrict__ bpart, int E, int NBH,
                                              const float* __restrict__ Wego,
                                              const float* __restrict__ Wconv,
                                              const float* __restrict__ Wcls,
                                              u16* __restrict__ WTin,
                                              u16* __restrict__ WT1,
                                              u16* __restrict__ WcatT) {
    if ((int)blockIdx.x < NBH) {
        __shared__ int lb[128];
        if (threadIdx.x < 128) lb[threadIdx.x] = 0;
        __syncthreads();
        const int eb = blockIdx.x * HCHUNK;
#pragma unroll
        for (int k = 0; k < 32; ++k) {
            int e = eb + k * 256 + threadIdx.x;
            if (e < E) atomicAdd(&lb[ei[E + e] >> BKT_SH], 1);
        }
        __syncthreads();
        if (threadIdx.x < 128)
            bpart[blockIdx.x * 128 + threadIdx.x] = lb[threadIdx.x];
    } else {
        int t = ((int)blockIdx.x - NBH) * 256 + threadIdx.x;
        if (t < 128 * 64) {
            int seg = t >> 6, d = t & 63;
            float v = (seg < 64) ? Wconv[d * 64 + seg] : Wego[d * 64 + (seg - 64)];
            WTin[t] = f2bf(v);
        } else if (t < 128 * 64 + 64 * 64) {
            int u = t - 128 * 64;
            int c = u >> 6, d = u & 63;
            WT1[u] = f2bf(Wconv[64 * 64 + d * 64 + c]);
        } else if (t < 128 * 64 + 64 * 64 + 48 * 192) {
            int u = t - (128 * 64 + 64 * 64);
            int c = u / 192, d = u - c * 192;
            WcatT[u] = f2bf(c < 40 ? Wcls[d * 40 + c] : 0.f);
        }
    }
}

// Parallel reduce of bpart (8 slices x 128 buckets, coalesced) + exclusive scan.
__global__ __launch_bounds__(1024) void k_bscan(const int* __restrict__ bpart, int NBH,
                                                int* __restrict__ bbase,
                                                int* __restrict__ bcursor, int NB) {
    __shared__ int part[8][128];
    __shared__ int s[128];
    const int t = threadIdx.x;
    const int bucket = t & 127, slice = t >> 7;
    int c = 0;
    for (int b = slice; b < NBH; b += 8) c += bpart[b * 128 + bucket];
    part[slice][bucket] = c;
    __syncthreads();
    int v = 0;
    if (t < 128) {
#pragma unroll
        for (int k = 0; k < 8; ++k) v += part[k][t];
        if (t >= NB) v = 0;
        s[t] = v;
    }
    __syncthreads();
    for (int st = 1; st < 128; st <<= 1) {
        int add = (t >= st && t < 128) ? s[t - st] : 0;
        __syncthreads();
        if (t < 128) s[t] += add;
        __syncthreads();
    }
    if (t < NB) {
        int excl = s[t] - v;
        bbase[t] = excl;
        bcursor[t] = excl;
        if (t == NB - 1) bbase[NB] = s[t];   // == E
    }
}

__global__ __launch_bounds__(256) void k_passA(const int* __restrict__ ei,
                                               int* __restrict__ bcursor,
                                               u32* __restrict__ sta, int E) {
    __shared__ int lcnt[128];
    __shared__ int lcur[128];
    if (threadIdx.x < 128) lcnt[threadIdx.x] = 0;
    __syncthreads();
    const int eb = blockIdx.x * CHUNK;
    int er[16], ec[16];
#pragma unroll
    for (int k = 0; k < 16; ++k) {
        int e = eb + k * 256 + threadIdx.x;
        if (e < E) {
            er[k] = ei[e];
            ec[k] = ei[E + e];
            atomicAdd(&lcnt[ec[k] >> BKT_SH], 1);
        } else {
            ec[k] = -1;
        }
    }
    __syncthreads();
    if (threadIdx.x < 128)
        lcur[threadIdx.x] = lcnt[threadIdx.x] > 0
                          ? atomicAdd(&bcursor[threadIdx.x], lcnt[threadIdx.x]) : 0;
    __syncthreads();
#pragma unroll
    for (int k = 0; k < 16; ++k) {
        if (ec[k] >= 0) {
            int pos = atomicAdd(&lcur[ec[k] >> BKT_SH], 1);
            sta[pos] = ((u32)(ec[k] & BKT_MASK) << 17) | (u32)er[k];
        }
    }
}

__global__ __launch_bounds__(256) void k_passB(const u32* __restrict__ sta,
                                               const int* __restrict__ bbase,
                                               int* __restrict__ indptr,
                                               float* __restrict__ dis,
                                               int* __restrict__ rows,
                                               int N, int NB) {
    __shared__ int lcnt[1024];
    __shared__ int cur[1024];
    __shared__ int ps[256];
    const int b = blockIdx.x;
    const int t = threadIdx.x;
    const int base = b << BKT_SH;
    const int e0 = bbase[b], e1 = bbase[b + 1];

#pragma unroll
    for (int k = 0; k < 4; ++k) lcnt[k * 256 + t] = 0;
    __syncthreads();
    for (int e = e0 + t; e < e1; e += 256)
        atomicAdd(&lcnt[sta[e] >> 17], 1);
    __syncthreads();

    int a0 = lcnt[t * 4 + 0], a1 = lcnt[t * 4 + 1];
    int a2 = lcnt[t * 4 + 2], a3 = lcnt[t * 4 + 3];
    int sum = a0 + a1 + a2 + a3;
    ps[t] = sum;
    __syncthreads();
    for (int st = 1; st < 256; st <<= 1) {
        int add = (t >= st) ? ps[t - st] : 0;
        __syncthreads();
        ps[t] += add;
        __syncthreads();
    }
    int ex = e0 + ps[t] - sum;
    int exs[4] = {ex, ex + a0, ex + a0 + a1, ex + a0 + a1 + a2};
    int cnts[4] = {a0, a1, a2, a3};
#pragma unroll
    for (int k = 0; k < 4; ++k) {
        int j = t * 4 + k;
        cur[j] = exs[k];
        int node = base + j;
        if (node < N) {
            indptr[node] = exs[k];
            dis[node] = rsqrtf((float)cnts[k] + 1.0f);   // self-loop adds 1
        }
    }
    if (b == NB - 1 && t == 0) indptr[N] = bbase[NB];    // == E
    __syncthreads();

    for (int e = e0 + t; e < e1; e += 256) {
        u32 v = sta[e];
        int pos = atomicAdd(&cur[v >> 17], 1);
        rows[pos] = (int)(v & 0x1FFFF);
    }
}

// ===========================================================================
// Fused cast + input layer (MFMA): reads x fp32, converts to bf16 frags.
// cols 0..63  -> hws1 [N][64] (bf16, dis-scaled)  [= dis * x@Wconv0]
// cols 64..127-> hall[:,0:64] (relu+bego)         [= P0]  (hall stride 192)
__global__ __launch_bounds__(256) void k_in(const float* __restrict__ x,
                                            const u16* __restrict__ WTin,
                                            const float* __restrict__ dis,
                                            const float* __restrict__ bego,
                                            u16* __restrict__ hws1,
                                            u16* __restrict__ hall, int N) {
    const int wid = (blockIdx.x * 256 + threadIdx.x) >> 6;
    const int l = threadIdx.x & 63;
    if (wid * 16 >= N) return;
    const int lr = l & 15;
    const int lk = l >> 4;

    int r_ld = wid * 16 + lr;
    if (r_ld >= N) r_ld = N - 1;
    const float* xrow = x + (size_t)r_ld * 64 + lk * 8;
    float4 u0 = *(const float4*)(xrow);
    float4 u1 = *(const float4*)(xrow + 4);
    float4 u2 = *(const float4*)(xrow + 32);
    float4 u3 = *(const float4*)(xrow + 36);
    short8 a0, a1;
    a0[0] = (short)f2bf(u0.x); a0[1] = (short)f2bf(u0.y);
    a0[2] = (short)f2bf(u0.z); a0[3] = (short)f2bf(u0.w);
    a0[4] = (short)f2bf(u1.x); a0[5] = (short)f2bf(u1.y);
    a0[6] = (short)f2bf(u1.z); a0[7] = (short)f2bf(u1.w);
    a1[0] = (short)f2bf(u2.x); a1[1] = (short)f2bf(u2.y);
    a1[2] = (short)f2bf(u2.z); a1[3] = (short)f2bf(u2.w);
    a1[4] = (short)f2bf(u3.x); a1[5] = (short)f2bf(u3.y);
    a1[6] = (short)f2bf(u3.z); a1[7] = (short)f2bf(u3.w);

    float dvals[4];
#pragma unroll
    for (int rg = 0; rg < 4; ++rg) {
        int r = wid * 16 + lk * 4 + rg;
        dvals[rg] = dis[r < N ? r : N - 1];
    }

    for (int ct = 0; ct < 8; ++ct) {
        const u16* wrow = WTin + ((size_t)(ct * 16 + lr)) * 64 + lk * 8;
        short8 b0 = *(const short8*)wrow;
        short8 b1 = *(const short8*)(wrow + 32);
        f32x4 acc = {0.f, 0.f, 0.f, 0.f};
        acc = __builtin_amdgcn_mfma_f32_16x16x32_bf16(a0, b0, acc, 0, 0, 0);
        acc = __builtin_amdgcn_mfma_f32_16x16x32_bf16(a1, b1, acc, 0, 0, 0);
        const int col = ct * 16 + lr;
        if (col < 64) {
#pragma unroll
            for (int rg = 0; rg < 4; ++rg) {
                int r = wid * 16 + lk * 4 + rg;
                if (r < N) hws1[(size_t)r * 64 + col] = f2bf(dvals[rg] * acc[rg]);
            }
        } else {
            float be = bego[col - 64];
#pragma unroll
            for (int rg = 0; rg < 4; ++rg) {
                int r = wid * 16 + lk * 4 + rg;
                if (r < N) hall[(size_t)r * 192 + (col - 64)] = f2bf(fmaxf(acc[rg] + be, 0.f));
            }
        }
    }
}

// ===========================================================================
// Gather v4: QUARTER-WAVE (16 lanes) per node. Lane owns a u64 = 4 bf16
// features; 16 lanes cover the 128B row; 4 nodes/wave -> 32 lines in flight
// per wave and 1 VMEM instr per 4 edges (vs per 2 in half-wave). Layout
// [N][64] unchanged (R15's sharding showed bytes aren't the currency).
__global__ __launch_bounds__(256) void k_gather(const int* __restrict__ indptr,
                                                const int* __restrict__ rows,
                                                const float* __restrict__ dis,
                                                const float* __restrict__ bconv,
                                                const u16* __restrict__ hws_in,
                                                u16* __restrict__ hdst, int N) {
    const int g = threadIdx.x >> 4;           // node group in block (0..15)
    const int c = threadIdx.x & 15;           // u64 index in row (features 4c..4c+3)
    const int i = blockIdx.x * 16 + g;
    if (i >= N) return;

    const u64* src = (const u64*)hws_in;      // row stride 16 u64
    u64 sv = src[(size_t)i * 16 + c];         // self-loop term
    u32 svl = (u32)sv, svh = (u32)(sv >> 32);
    float a0 = bflo(svl), a1 = bfhi(svl), a2 = bflo(svh), a3 = bfhi(svh);

    int p0 = indptr[i], p1 = indptr[i + 1];   // uniform within group
    int p = p0;
    for (; p + 8 <= p1; p += 8) {
        int r0 = rows[p + 0], r1 = rows[p + 1], r2 = rows[p + 2], r3 = rows[p + 3];
        int r4 = rows[p + 4], r5 = rows[p + 5], r6 = rows[p + 6], r7 = rows[p + 7];
        u64 v0 = src[(size_t)r0 * 16 + c];
        u64 v1 = src[(size_t)r1 * 16 + c];
        u64 v2 = src[(size_t)r2 * 16 + c];
        u64 v3 = src[(size_t)r3 * 16 + c];
        u64 v4 = src[(size_t)r4 * 16 + c];
        u64 v5 = src[(size_t)r5 * 16 + c];
        u64 v6 = src[(size_t)r6 * 16 + c];
        u64 v7 = src[(size_t)r7 * 16 + c];
        u32 l0 = (u32)v0, h0_ = (u32)(v0 >> 32);
        u32 l1 = (u32)v1, h1_ = (u32)(v1 >> 32);
        u32 l2 = (u32)v2, h2_ = (u32)(v2 >> 32);
        u32 l3 = (u32)v3, h3_ = (u32)(v3 >> 32);
        u32 l4 = (u32)v4, h4_ = (u32)(v4 >> 32);
        u32 l5 = (u32)v5, h5_ = (u32)(v5 >> 32);
        u32 l6 = (u32)v6, h6_ = (u32)(v6 >> 32);
        u32 l7 = (u32)v7, h7_ = (u32)(v7 >> 32);
        a0 += ((bflo(l0) + bflo(l1)) + (bflo(l2) + bflo(l3))) +
              ((bflo(l4) + bflo(l5)) + (bflo(l6) + bflo(l7)));
        a1 += ((bfhi(l0) + bfhi(l1)) + (bfhi(l2) + bfhi(l3))) +
              ((bfhi(l4) + bfhi(l5)) + (bfhi(l6) + bfhi(l7)));
        a2 += ((bflo(h0_) + bflo(h1_)) + (bflo(h2_) + bflo(h3_))) +
              ((bflo(h4_) + bflo(h5_)) + (bflo(h6_) + bflo(h7_)));
        a3 += ((bfhi(h0_) + bfhi(h1_)) + (bfhi(h2_) + bfhi(h3_))) +
              ((bfhi(h4_) + bfhi(h5_)) + (bfhi(h6_) + bfhi(h7_)));
    }
    for (; p + 4 <= p1; p += 4) {
        int r0 = rows[p + 0], r1 = rows[p + 1], r2 = rows[p + 2], r3 = rows[p + 3];
        u64 v0 = src[(size_t)r0 * 16 + c];
        u64 v1 = src[(size_t)r1 * 16 + c];
        u64 v2 = src[(size_t)r2 * 16 + c];
        u64 v3 = src[(size_t)r3 * 16 + c];
        u32 l0 = (u32)v0, h0_ = (u32)(v0 >> 32);
        u32 l1 = (u32)v1, h1_ = (u32)(v1 >> 32);
        u32 l2 = (u32)v2, h2_ = (u32)(v2 >> 32);
        u32 l3 = (u32)v3, h3_ = (u32)(v3 >> 32);
        a0 += (bflo(l0) + bflo(l1)) + (bflo(l2) + bflo(l3));
        a1 += (bfhi(l0) + bfhi(l1)) + (bfhi(l2) + bfhi(l3));
        a2 += (bflo(h0_) + bflo(h1_)) + (bflo(h2_) + bflo(h3_));
        a3 += (bfhi(h0_) + bfhi(h1_)) + (bfhi(h2_) + bfhi(h3_));
    }
    for (; p < p1; ++p) {
        u64 v = src[(size_t)rows[p] * 16 + c];
        u32 l = (u32)v, h = (u32)(v >> 32);
        a0 += bflo(l); a1 += bfhi(l); a2 += bflo(h); a3 += bfhi(h);
    }

    float dsi = dis[i];
    float4 bb = *(const float4*)(bconv + 4 * c);
    float h0 = fmaxf(fmaf(dsi, a0, bb.x), 0.0f);
    float h1 = fmaxf(fmaf(dsi, a1, bb.y), 0.0f);
    float h2 = fmaxf(fmaf(dsi, a2, bb.z), 0.0f);
    float h3 = fmaxf(fmaf(dsi, a3, bb.w), 0.0f);
    u64 outv = (u64)f2bf(h0) | ((u64)f2bf(h1) << 16)
             | ((u64)f2bf(h2) << 32) | ((u64)f2bf(h3) << 48);
    ((u64*)hdst)[(size_t)i * 48 + c] = outv;   // hdst = hall+64/128: stride 192 u16
}

// ===========================================================================
// hws2 = bf16(dis * (h1 @ Wconv1)), h1 = hall[:,64:128].
__global__ __launch_bounds__(256) void k_next1(const u16* __restrict__ hall,
                                               const u16* __restrict__ WT1,
                                               const float* __restrict__ dis,
                                               u16* __restrict__ hws, int N) {
    const int wid = (blockIdx.x * 256 + threadIdx.x) >> 6;
    const int l = threadIdx.x & 63;
    if (wid * 16 >= N) return;
    const int lr = l & 15;
    const int lk = l >> 4;

    int r_ld = wid * 16 + lr;
    if (r_ld >= N) r_ld = N - 1;
    const u16* arow = hall + (size_t)r_ld * 192 + 64 + lk * 8;
    short8 a0 = *(const short8*)arow;
    short8 a1 = *(const short8*)(arow + 32);

    float dvals[4];
#pragma unroll
    for (int rg = 0; rg < 4; ++rg) {
        int r = wid * 16 + lk * 4 + rg;
        dvals[rg] = dis[r < N ? r : N - 1];
    }

    for (int ct = 0; ct < 4; ++ct) {
        const u16* wrow = WT1 + ((size_t)(ct * 16 + lr)) * 64 + lk * 8;
        short8 b0 = *(const short8*)wrow;
        short8 b1 = *(const short8*)(wrow + 32);
        f32x4 acc = {0.f, 0.f, 0.f, 0.f};
        acc = __builtin_amdgcn_mfma_f32_16x16x32_bf16(a0, b0, acc, 0, 0, 0);
        acc = __builtin_amdgcn_mfma_f32_16x16x32_bf16(a1, b1, acc, 0, 0, 0);
        const int col = ct * 16 + lr;
#pragma unroll
        for (int rg = 0; rg < 4; ++rg) {
            int r = wid * 16 + lk * 4 + rg;
            if (r < N) hws[(size_t)r * 64 + col] = f2bf(dvals[rg] * acc[rg]);
        }
    }
}

// ===========================================================================
// Final classifier: out = bcls + hall[N,192] @ Wcls[192,40]. Single write.
__global__ __launch_bounds__(256) void k_clsall(const u16* __restrict__ hall,
                                                const u16* __restrict__ WcatT,
                                                const float* __restrict__ bcls,
                                                float* __restrict__ out, int N) {
    const int wid = (blockIdx.x * 256 + threadIdx.x) >> 6;
    const int l = threadIdx.x & 63;
    if (wid * 16 >= N) return;
    const int lr = l & 15;
    const int lk = l >> 4;

    int r_ld = wid * 16 + lr;
    if (r_ld >= N) r_ld = N - 1;
    const u16* arow = hall + (size_t)r_ld * 192 + lk * 8;
    short8 a[6];
#pragma unroll
    for (int kt = 0; kt < 6; ++kt) a[kt] = *(const short8*)(arow + kt * 32);

    for (int ct = 0; ct < 3; ++ct) {
        const u16* brow = WcatT + ((size_t)(ct * 16 + lr)) * 192 + lk * 8;
        f32x4 acc = {0.f, 0.f, 0.f, 0.f};
#pragma unroll
        for (int kt = 0; kt < 6; ++kt) {
            short8 b = *(const short8*)(brow + kt * 32);
            acc = __builtin_amdgcn_mfma_f32_16x16x32_bf16(a[kt], b, acc, 0, 0, 0);
        }
        const int col = ct * 16 + lr;
        if (col < 40) {
            float bc = bcls[col];
#pragma unroll
            for (int rg = 0; rg < 4; ++rg) {
                int r = wid * 16 + lk * 4 + rg;
                if (r < N) out[(size_t)r * 40 + col] = bc + acc[rg];
            }
        }
    }
}

// ===========================================================================
extern "C" void kernel_launch(void* const* d_in, const int* in_sizes, int n_in,
                              void* d_out, int out_size, void* d_ws, size_t ws_size,
                              hipStream_t stream) {
    const float* x     = (const float*)d_in[0];
    const int*   ei    = (const int*)d_in[1];   // [2,E] int32
    const float* Wego  = (const float*)d_in[2];
    const float* bego  = (const float*)d_in[3];
    const float* Wconv = (const float*)d_in[4]; // [2,64,64]
    const float* bconv = (const float*)d_in[5]; // [2,64]
    const float* Wcls  = (const float*)d_in[6]; // [192,40]
    const float* bcls  = (const float*)d_in[7];
    float* out = (float*)d_out;

    const int N = in_sizes[0] / 64;
    const int E = in_sizes[1] / 2;
    const int NB   = cdiv(N, 1 << BKT_SH);      // buckets (98)
    const int NBH  = cdiv(E, HCHUNK);           // histogram blocks (153)
    const int NBA  = cdiv(E, CHUNK);            // passA blocks (306)

    // workspace layout (u16 units unless noted):
    //  hall u16[N*192]  (aliased early: sta u32[E], dead before k_in)
    //  hws1 u16[N*64] | hws2 u16[N*64] |
    //  WTin[128*64] | WT1[64*64] | WcatT[48*192] |
    //  dis f[N] | indptr i[N+1+pad] | bbase i[132] | bcursor i[128] |
    //  rows i[E] | bpart i[NBH*128]
    u16* hall  = (u16*)d_ws;
    u32* sta   = (u32*)d_ws;                    // alias, dead before k_in
    u16* hws1  = hall + (size_t)N * 192;
    u16* hws2  = hws1 + (size_t)N * 64;
    u16* WTin  = hws2 + (size_t)N * 64;
    u16* WT1   = WTin + 128 * 64;
    u16* WcatT = WT1 + 64 * 64;
    float* dis = (float*)(WcatT + 48 * 192);
    int* indptr  = (int*)(dis + N);
    int* bbase   = indptr + N + 64;
    int* bcursor = bbase + 132;
    int* rows    = bcursor + 128;
    int* bpart   = rows + E;

    // ---- CSR build + weight prep (no memset: bpart is non-atomic) ----
    const int PREP_BLOCKS = cdiv(128 * 64 + 64 * 64 + 48 * 192, 256);
    k_init<<<NBH + PREP_BLOCKS, 256, 0, stream>>>(ei, bpart, E, NBH,
                                                  Wego, Wconv, Wcls, WTin, WT1, WcatT);
    k_bscan<<<1, 1024, 0, stream>>>(bpart, NBH, bbase, bcursor, NB);
    k_passA<<<NBA, 256, 0, stream>>>(ei, bcursor, sta, E);
    k_passB<<<NB, 256, 0, stream>>>(sta, bbase, indptr, dis, rows, N, NB);

    // ---- input layer (fused cast, MFMA) ----
    k_in<<<cdiv(cdiv(N, 16), 4), 256, 0, stream>>>(x, WTin, dis, bego, hws1, hall, N);

    // ---- hop 1: gather -> h1 (hall slice 1); hws2 = dis*(h1@Wconv1) ----
    k_gather<<<cdiv(N, 16), 256, 0, stream>>>(indptr, rows, dis, bconv,
                                              hws1, hall + 64, N);
    k_next1<<<cdiv(cdiv(N, 16), 4), 256, 0, stream>>>(hall, WT1, dis, hws2, N);

    // ---- hop 2: gather -> h2 (hall slice 2) ----
    k_gather<<<cdiv(N, 16), 256, 0, stream>>>(indptr, rows, dis, bconv + 64,
                                              hws2, hall + 128, N);

    // ---- classifier: out = bcls + hall @ Wcls (single pass) ----
    k_clsall<<<cdiv(cdiv(N, 16), 4), 256, 0, stream>>>(hall, WcatT, bcls, out, N);
}

// Round 17
// 184.808 us; speedup vs baseline: 1.3018x; 1.0115x over previous
//
#include <hip/hip_runtime.h>

using u16 = unsigned short;
using u32 = unsigned int;
using u64 = unsigned long long;
using short8 = __attribute__((ext_vector_type(8))) short;
using f32x4  = __attribute__((ext_vector_type(4))) float;
using u32x4  = __attribute__((ext_vector_type(4))) unsigned int;

static inline int cdiv(long long a, long long b) { return (int)((a + b - 1) / b); }

__device__ __forceinline__ u16 f2bf(float x) {
    u32 u = __builtin_bit_cast(u32, x);
    u += 0x7fffu + ((u >> 16) & 1u);   // RTNE
    return (u16)(u >> 16);
}
__device__ __forceinline__ float bf2f(u16 h) {
    u32 u = ((u32)h) << 16;
    return __builtin_bit_cast(float, u);
}
__device__ __forceinline__ float bflo(u32 v) {
    return __builtin_bit_cast(float, v << 16);
}
__device__ __forceinline__ float bfhi(u32 v) {
    return __builtin_bit_cast(float, v & 0xffff0000u);
}

// ===========================================================================
// CSR build, 2-level counting sort. Bucket = 1024 destination nodes.
// Staging word: (c & 1023) << 17 | r   -- requires N < 131072.
#define BKT_SH 10
#define BKT_MASK ((1 << BKT_SH) - 1)
#define HCHUNK 8192     // k_init histogram chunk
#define CHUNK 4096      // passA chunk

// Fused: [blocks 0..NBH) edge-bucket histogram -> bpart (non-atomic partials,
// no pre-zero needed); [blocks NBH..) transposed bf16 weight panel prep.
__global__ __launch_bounds__(256) void k_init(const int* __restrict__ ei,
                                              int* __restrict__ bpart, int E, int NBH,
                                              const float* __restrict__ Wego,
                                              const float* __restrict__ Wconv,
                                              const float* __restrict__ Wcls,
                                              u16* __restrict__ WTin,
                                              u16* __restrict__ WT1,
                                              u16* __restrict__ WcatT) {
    if ((int)blockIdx.x < NBH) {
        __shared__ int lb[128];
        if (threadIdx.x < 128) lb[threadIdx.x] = 0;
        __syncthreads();
        const int eb = blockIdx.x * HCHUNK;
#pragma unroll
        for (int k = 0; k < 32; ++k) {
            int e = eb + k * 256 + threadIdx.x;
            if (e < E) atomicAdd(&lb[ei[E + e] >> BKT_SH], 1);
        }
        __syncthreads();
        if (threadIdx.x < 128)
            bpart[blockIdx.x * 128 + threadIdx.x] = lb[threadIdx.x];
    } else {
        int t = ((int)blockIdx.x - NBH) * 256 + threadIdx.x;
        if (t < 128 * 64) {
            int seg = t >> 6, d = t & 63;
            float v = (seg < 64) ? Wconv[d * 64 + seg] : Wego[d * 64 + (seg - 64)];
            WTin[t] = f2bf(v);
        } else if (t < 128 * 64 + 64 * 64) {
            int u = t - 128 * 64;
            int c = u >> 6, d = u & 63;
            WT1[u] = f2bf(Wconv[64 * 64 + d * 64 + c]);
        } else if (t < 128 * 64 + 64 * 64 + 48 * 192) {
            int u = t - (128 * 64 + 64 * 64);
            int c = u / 192, d = u - c * 192;
            WcatT[u] = f2bf(c < 40 ? Wcls[d * 40 + c] : 0.f);
        }
    }
}

// Parallel reduce of bpart (8 slices x 128 buckets, coalesced) + exclusive scan.
__global__ __launch_bounds__(1024) void k_bscan(const int* __restrict__ bpart, int NBH,
                                                int* __restrict__ bbase,
                                                int* __restrict__ bcursor, int NB) {
    __shared__ int part[8][128];
    __shared__ int s[128];
    const int t = threadIdx.x;
    const int bucket = t & 127, slice = t >> 7;
    int c = 0;
    for (int b = slice; b < NBH; b += 8) c += bpart[b * 128 + bucket];
    part[slice][bucket] = c;
    __syncthreads();
    int v = 0;
    if (t < 128) {
#pragma unroll
        for (int k = 0; k < 8; ++k) v += part[k][t];
        if (t >= NB) v = 0;
        s[t] = v;
    }
    __syncthreads();
    for (int st = 1; st < 128; st <<= 1) {
        int add = (t >= st && t < 128) ? s[t - st] : 0;
        __syncthreads();
        if (t < 128) s[t] += add;
        __syncthreads();
    }
    if (t < NB) {
        int excl = s[t] - v;
        bbase[t] = excl;
        bcursor[t] = excl;
        if (t == NB - 1) bbase[NB] = s[t];   // == E
    }
}

__global__ __launch_bounds__(256) void k_passA(const int* __restrict__ ei,
                                               int* __restrict__ bcursor,
                                               u32* __restrict__ sta, int E) {
    __shared__ int lcnt[128];
    __shared__ int lcur[128];
    if (threadIdx.x < 128) lcnt[threadIdx.x] = 0;
    __syncthreads();
    const int eb = blockIdx.x * CHUNK;
    int er[16], ec[16];
#pragma unroll
    for (int k = 0; k < 16; ++k) {
        int e = eb + k * 256 + threadIdx.x;
        if (e < E) {
            er[k] = ei[e];
            ec[k] = ei[E + e];
            atomicAdd(&lcnt[ec[k] >> BKT_SH], 1);
        } else {
            ec[k] = -1;
        }
    }
    __syncthreads();
    if (threadIdx.x < 128)
        lcur[threadIdx.x] = lcnt[threadIdx.x] > 0
                          ? atomicAdd(&bcursor[threadIdx.x], lcnt[threadIdx.x]) : 0;
    __syncthreads();
#pragma unroll
    for (int k = 0; k < 16; ++k) {
        if (ec[k] >= 0) {
            int pos = atomicAdd(&lcur[ec[k] >> BKT_SH], 1);
            sta[pos] = ((u32)(ec[k] & BKT_MASK) << 17) | (u32)er[k];
        }
    }
}

__global__ __launch_bounds__(256) void k_passB(const u32* __restrict__ sta,
                                               const int* __restrict__ bbase,
                                               int* __restrict__ indptr,
                                               float* __restrict__ dis,
                                               int* __restrict__ rows,
                                               int N, int NB) {
    __shared__ int lcnt[1024];
    __shared__ int cur[1024];
    __shared__ int ps[256];
    const int b = blockIdx.x;
    const int t = threadIdx.x;
    const int base = b << BKT_SH;
    const int e0 = bbase[b], e1 = bbase[b + 1];

#pragma unroll
    for (int k = 0; k < 4; ++k) lcnt[k * 256 + t] = 0;
    __syncthreads();
    for (int e = e0 + t; e < e1; e += 256)
        atomicAdd(&lcnt[sta[e] >> 17], 1);
    __syncthreads();

    int a0 = lcnt[t * 4 + 0], a1 = lcnt[t * 4 + 1];
    int a2 = lcnt[t * 4 + 2], a3 = lcnt[t * 4 + 3];
    int sum = a0 + a1 + a2 + a3;
    ps[t] = sum;
    __syncthreads();
    for (int st = 1; st < 256; st <<= 1) {
        int add = (t >= st) ? ps[t - st] : 0;
        __syncthreads();
        ps[t] += add;
        __syncthreads();
    }
    int ex = e0 + ps[t] - sum;
    int exs[4] = {ex, ex + a0, ex + a0 + a1, ex + a0 + a1 + a2};
    int cnts[4] = {a0, a1, a2, a3};
#pragma unroll
    for (int k = 0; k < 4; ++k) {
        int j = t * 4 + k;
        cur[j] = exs[k];
        int node = base + j;
        if (node < N) {
            indptr[node] = exs[k];
            dis[node] = rsqrtf((float)cnts[k] + 1.0f);   // self-loop adds 1
        }
    }
    if (b == NB - 1 && t == 0) indptr[N] = bbase[NB];    // == E
    __syncthreads();

    for (int e = e0 + t; e < e1; e += 256) {
        u32 v = sta[e];
        int pos = atomicAdd(&cur[v >> 17], 1);
        rows[pos] = (int)(v & 0x1FFFF);
    }
}

// ===========================================================================
// Fused cast + input layer (MFMA): reads x fp32, converts to bf16 frags.
// cols 0..63  -> hws1 [N][64] (bf16, dis-scaled)  [= dis * x@Wconv0]
// cols 64..127-> hall[:,0:64] (relu+bego)         [= P0]  (hall stride 192)
__global__ __launch_bounds__(256) void k_in(const float* __restrict__ x,
                                            const u16* __restrict__ WTin,
                                            const float* __restrict__ dis,
                                            const float* __restrict__ bego,
                                            u16* __restrict__ hws1,
                                            u16* __restrict__ hall, int N) {
    const int wid = (blockIdx.x * 256 + threadIdx.x) >> 6;
    const int l = threadIdx.x & 63;
    if (wid * 16 >= N) return;
    const int lr = l & 15;
    const int lk = l >> 4;

    int r_ld = wid * 16 + lr;
    if (r_ld >= N) r_ld = N - 1;
    const float* xrow = x + (size_t)r_ld * 64 + lk * 8;
    float4 u0 = *(const float4*)(xrow);
    float4 u1 = *(const float4*)(xrow + 4);
    float4 u2 = *(const float4*)(xrow + 32);
    float4 u3 = *(const float4*)(xrow + 36);
    short8 a0, a1;
    a0[0] = (short)f2bf(u0.x); a0[1] = (short)f2bf(u0.y);
    a0[2] = (short)f2bf(u0.z); a0[3] = (short)f2bf(u0.w);
    a0[4] = (short)f2bf(u1.x); a0[5] = (short)f2bf(u1.y);
    a0[6] = (short)f2bf(u1.z); a0[7] = (short)f2bf(u1.w);
    a1[0] = (short)f2bf(u2.x); a1[1] = (short)f2bf(u2.y);
    a1[2] = (short)f2bf(u2.z); a1[3] = (short)f2bf(u2.w);
    a1[4] = (short)f2bf(u3.x); a1[5] = (short)f2bf(u3.y);
    a1[6] = (short)f2bf(u3.z); a1[7] = (short)f2bf(u3.w);

    float dvals[4];
#pragma unroll
    for (int rg = 0; rg < 4; ++rg) {
        int r = wid * 16 + lk * 4 + rg;
        dvals[rg] = dis[r < N ? r : N - 1];
    }

    for (int ct = 0; ct < 8; ++ct) {
        const u16* wrow = WTin + ((size_t)(ct * 16 + lr)) * 64 + lk * 8;
        short8 b0 = *(const short8*)wrow;
        short8 b1 = *(const short8*)(wrow + 32);
        f32x4 acc = {0.f, 0.f, 0.f, 0.f};
        acc = __builtin_amdgcn_mfma_f32_16x16x32_bf16(a0, b0, acc, 0, 0, 0);
        acc = __builtin_amdgcn_mfma_f32_16x16x32_bf16(a1, b1, acc, 0, 0, 0);
        const int col = ct * 16 + lr;
        if (col < 64) {
#pragma unroll
            for (int rg = 0; rg < 4; ++rg) {
                int r = wid * 16 + lk * 4 + rg;
                if (r < N) hws1[(size_t)r * 64 + col] = f2bf(dvals[rg] * acc[rg]);
            }
        } else {
            float be = bego[col - 64];
#pragma unroll
            for (int rg = 0; rg < 4; ++rg) {
                int r = wid * 16 + lk * 4 + rg;
                if (r < N) hall[(size_t)r * 192 + (col - 64)] = f2bf(fmaxf(acc[rg] + be, 0.f));
            }
        }
    }
}

// ===========================================================================
// Gather v5: EIGHTH-WAVE (8 lanes) per node, 16B u32x4 loads. Lane owns 8
// bf16 features; 8 lanes cover the 128B row; 8 nodes/wave -> 64 rows in
// flight per wave and 1 VMEM instr per 8 edge-rows. 16B/lane = coalescing
// sweet spot. Layout [N][64] (R15 showed bytes aren't the currency).
__global__ __launch_bounds__(256) void k_gather(const int* __restrict__ indptr,
                                                const int* __restrict__ rows,
                                                const float* __restrict__ dis,
                                                const float* __restrict__ bconv,
                                                const u16* __restrict__ hws_in,
                                                u16* __restrict__ hdst, int N) {
    const int g = threadIdx.x >> 3;           // node group in block (0..31)
    const int c = threadIdx.x & 7;            // u32x4 index in row (features 8c..8c+7)
    const int i = blockIdx.x * 32 + g;
    if (i >= N) return;

    const u32x4* src = (const u32x4*)hws_in;  // row stride 8 u32x4
    u32x4 sv = src[(size_t)i * 8 + c];        // self-loop term
    float a0 = bflo(sv.x), a1 = bfhi(sv.x), a2 = bflo(sv.y), a3 = bfhi(sv.y);
    float a4 = bflo(sv.z), a5 = bfhi(sv.z), a6 = bflo(sv.w), a7 = bfhi(sv.w);

    int p0 = indptr[i], p1 = indptr[i + 1];   // uniform within group
    int p = p0;
    for (; p + 8 <= p1; p += 8) {
        int r0 = rows[p + 0], r1 = rows[p + 1], r2 = rows[p + 2], r3 = rows[p + 3];
        int r4 = rows[p + 4], r5 = rows[p + 5], r6 = rows[p + 6], r7 = rows[p + 7];
        u32x4 v0 = src[(size_t)r0 * 8 + c];
        u32x4 v1 = src[(size_t)r1 * 8 + c];
        u32x4 v2 = src[(size_t)r2 * 8 + c];
        u32x4 v3 = src[(size_t)r3 * 8 + c];
        u32x4 v4 = src[(size_t)r4 * 8 + c];
        u32x4 v5 = src[(size_t)r5 * 8 + c];
        u32x4 v6 = src[(size_t)r6 * 8 + c];
        u32x4 v7 = src[(size_t)r7 * 8 + c];
        a0 += ((bflo(v0.x) + bflo(v1.x)) + (bflo(v2.x) + bflo(v3.x))) +
              ((bflo(v4.x) + bflo(v5.x)) + (bflo(v6.x) + bflo(v7.x)));
        a1 += ((bfhi(v0.x) + bfhi(v1.x)) + (bfhi(v2.x) + bfhi(v3.x))) +
              ((bfhi(v4.x) + bfhi(v5.x)) + (bfhi(v6.x) + bfhi(v7.x)));
        a2 += ((bflo(v0.y) + bflo(v1.y)) + (bflo(v2.y) + bflo(v3.y))) +
              ((bflo(v4.y) + bflo(v5.y)) + (bflo(v6.y) + bflo(v7.y)));
        a3 += ((bfhi(v0.y) + bfhi(v1.y)) + (bfhi(v2.y) + bfhi(v3.y))) +
              ((bfhi(v4.y) + bfhi(v5.y)) + (bfhi(v6.y) + bfhi(v7.y)));
        a4 += ((bflo(v0.z) + bflo(v1.z)) + (bflo(v2.z) + bflo(v3.z))) +
              ((bflo(v4.z) + bflo(v5.z)) + (bflo(v6.z) + bflo(v7.z)));
        a5 += ((bfhi(v0.z) + bfhi(v1.z)) + (bfhi(v2.z) + bfhi(v3.z))) +
              ((bfhi(v4.z) + bfhi(v5.z)) + (bfhi(v6.z) + bfhi(v7.z)));
        a6 += ((bflo(v0.w) + bflo(v1.w)) + (bflo(v2.w) + bflo(v3.w))) +
              ((bflo(v4.w) + bflo(v5.w)) + (bflo(v6.w) + bflo(v7.w)));
        a7 += ((bfhi(v0.w) + bfhi(v1.w)) + (bfhi(v2.w) + bfhi(v3.w))) +
              ((bfhi(v4.w) + bfhi(v5.w)) + (bfhi(v6.w) + bfhi(v7.w)));
    }
    for (; p + 4 <= p1; p += 4) {
        int r0 = rows[p + 0], r1 = rows[p + 1], r2 = rows[p + 2], r3 = rows[p + 3];
        u32x4 v0 = src[(size_t)r0 * 8 + c];
        u32x4 v1 = src[(size_t)r1 * 8 + c];
        u32x4 v2 = src[(size_t)r2 * 8 + c];
        u32x4 v3 = src[(size_t)r3 * 8 + c];
        a0 += (bflo(v0.x) + bflo(v1.x)) + (bflo(v2.x) + bflo(v3.x));
        a1 += (bfhi(v0.x) + bfhi(v1.x)) + (bfhi(v2.x) + bfhi(v3.x));
        a2 += (bflo(v0.y) + bflo(v1.y)) + (bflo(v2.y) + bflo(v3.y));
        a3 += (bfhi(v0.y) + bfhi(v1.y)) + (bfhi(v2.y) + bfhi(v3.y));
        a4 += (bflo(v0.z) + bflo(v1.z)) + (bflo(v2.z) + bflo(v3.z));
        a5 += (bfhi(v0.z) + bfhi(v1.z)) + (bfhi(v2.z) + bfhi(v3.z));
        a6 += (bflo(v0.w) + bflo(v1.w)) + (bflo(v2.w) + bflo(v3.w));
        a7 += (bfhi(v0.w) + bfhi(v1.w)) + (bfhi(v2.w) + bfhi(v3.w));
    }
    for (; p < p1; ++p) {
        u32x4 v = src[(size_t)rows[p] * 8 + c];
        a0 += bflo(v.x); a1 += bfhi(v.x); a2 += bflo(v.y); a3 += bfhi(v.y);
        a4 += bflo(v.z); a5 += bfhi(v.z); a6 += bflo(v.w); a7 += bfhi(v.w);
    }

    float dsi = dis[i];
    float4 bb0 = *(const float4*)(bconv + 8 * c);
    float4 bb1 = *(const float4*)(bconv + 8 * c + 4);
    u32x4 outv;
    outv.x = (u32)f2bf(fmaxf(fmaf(dsi, a0, bb0.x), 0.0f))
           | ((u32)f2bf(fmaxf(fmaf(dsi, a1, bb0.y), 0.0f)) << 16);
    outv.y = (u32)f2bf(fmaxf(fmaf(dsi, a2, bb0.z), 0.0f))
           | ((u32)f2bf(fmaxf(fmaf(dsi, a3, bb0.w), 0.0f)) << 16);
    outv.z = (u32)f2bf(fmaxf(fmaf(dsi, a4, bb1.x), 0.0f))
           | ((u32)f2bf(fmaxf(fmaf(dsi, a5, bb1.y), 0.0f)) << 16);
    outv.w = (u32)f2bf(fmaxf(fmaf(dsi, a6, bb1.z), 0.0f))
           | ((u32)f2bf(fmaxf(fmaf(dsi, a7, bb1.w), 0.0f)) << 16);
    ((u32x4*)hdst)[(size_t)i * 24 + c] = outv;   // hdst stride 192 u16 = 24 u32x4
}

// ===========================================================================
// hws2 = bf16(dis * (h1 @ Wconv1)), h1 = hall[:,64:128].
__global__ __launch_bounds__(256) void k_next1(const u16* __restrict__ hall,
                                               const u16* __restrict__ WT1,
                                               const float* __restrict__ dis,
                                               u16* __restrict__ hws, int N) {
    const int wid = (blockIdx.x * 256 + threadIdx.x) >> 6;
    const int l = threadIdx.x & 63;
    if (wid * 16 >= N) return;
    const int lr = l & 15;
    const int lk = l >> 4;

    int r_ld = wid * 16 + lr;
    if (r_ld >= N) r_ld = N - 1;
    const u16* arow = hall + (size_t)r_ld * 192 + 64 + lk * 8;
    short8 a0 = *(const short8*)arow;
    short8 a1 = *(const short8*)(arow + 32);

    float dvals[4];
#pragma unroll
    for (int rg = 0; rg < 4; ++rg) {
        int r = wid * 16 + lk * 4 + rg;
        dvals[rg] = dis[r < N ? r : N - 1];
    }

    for (int ct = 0; ct < 4; ++ct) {
        const u16* wrow = WT1 + ((size_t)(ct * 16 + lr)) * 64 + lk * 8;
        short8 b0 = *(const short8*)wrow;
        short8 b1 = *(const short8*)(wrow + 32);
        f32x4 acc = {0.f, 0.f, 0.f, 0.f};
        acc = __builtin_amdgcn_mfma_f32_16x16x32_bf16(a0, b0, acc, 0, 0, 0);
        acc = __builtin_amdgcn_mfma_f32_16x16x32_bf16(a1, b1, acc, 0, 0, 0);
        const int col = ct * 16 + lr;
#pragma unroll
        for (int rg = 0; rg < 4; ++rg) {
            int r = wid * 16 + lk * 4 + rg;
            if (r < N) hws[(size_t)r * 64 + col] = f2bf(dvals[rg] * acc[rg]);
        }
    }
}

// ===========================================================================
// Final classifier: out = bcls + hall[N,192] @ Wcls[192,40]. Single write.
__global__ __launch_bounds__(256) void k_clsall(const u16* __restrict__ hall,
                                                const u16* __restrict__ WcatT,
                                                const float* __restrict__ bcls,
                                                float* __restrict__ out, int N) {
    const int wid = (blockIdx.x * 256 + threadIdx.x) >> 6;
    const int l = threadIdx.x & 63;
    if (wid * 16 >= N) return;
    const int lr = l & 15;
    const int lk = l >> 4;

    int r_ld = wid * 16 + lr;
    if (r_ld >= N) r_ld = N - 1;
    const u16* arow = hall + (size_t)r_ld * 192 + lk * 8;
    short8 a[6];
#pragma unroll
    for (int kt = 0; kt < 6; ++kt) a[kt] = *(const short8*)(arow + kt * 32);

    for (int ct = 0; ct < 3; ++ct) {
        const u16* brow = WcatT + ((size_t)(ct * 16 + lr)) * 192 + lk * 8;
        f32x4 acc = {0.f, 0.f, 0.f, 0.f};
#pragma unroll
        for (int kt = 0; kt < 6; ++kt) {
            short8 b = *(const short8*)(brow + kt * 32);
            acc = __builtin_amdgcn_mfma_f32_16x16x32_bf16(a[kt], b, acc, 0, 0, 0);
        }
        const int col = ct * 16 + lr;
        if (col < 40) {
            float bc = bcls[col];
#pragma unroll
            for (int rg = 0; rg < 4; ++rg) {
                int r = wid * 16 + lk * 4 + rg;
                if (r < N) out[(size_t)r * 40 + col] = bc + acc[rg];
            }
        }
    }
}

// ===========================================================================
extern "C" void kernel_launch(void* const* d_in, const int* in_sizes, int n_in,
                              void* d_out, int out_size, void* d_ws, size_t ws_size,
                              hipStream_t stream) {
    const float* x     = (const float*)d_in[0];
    const int*   ei    = (const int*)d_in[1];   // [2,E] int32
    const float* Wego  = (const float*)d_in[2];
    const float* bego  = (const float*)d_in[3];
    const float* Wconv = (const float*)d_in[4]; // [2,64,64]
    const float* bconv = (const float*)d_in[5]; // [2,64]
    const float* Wcls  = (const float*)d_in[6]; // [192,40]
    const float* bcls  = (const float*)d_in[7];
    float* out = (float*)d_out;

    const int N = in_sizes[0] / 64;
    const int E = in_sizes[1] / 2;
    const int NB   = cdiv(N, 1 << BKT_SH);      // buckets (98)
    const int NBH  = cdiv(E, HCHUNK);           // histogram blocks (153)
    const int NBA  = cdiv(E, CHUNK);            // passA blocks (306)

    // workspace layout (u16 units unless noted):
    //  hall u16[N*192]  (aliased early: sta u32[E], dead before k_in)
    //  hws1 u16[N*64] | hws2 u16[N*64] |
    //  WTin[128*64] | WT1[64*64] | WcatT[48*192] |
    //  dis f[N] | indptr i[N+1+pad] | bbase i[132] | bcursor i[128] |
    //  rows i[E] | bpart i[NBH*128]
    u16* hall  = (u16*)d_ws;
    u32* sta   = (u32*)d_ws;                    // alias, dead before k_in
    u16* hws1  = hall + (size_t)N * 192;
    u16* hws2  = hws1 + (size_t)N * 64;
    u16* WTin  = hws2 + (size_t)N * 64;
    u16* WT1   = WTin + 128 * 64;
    u16* WcatT = WT1 + 64 * 64;
    float* dis = (float*)(WcatT + 48 * 192);
    int* indptr  = (int*)(dis + N);
    int* bbase   = indptr + N + 64;
    int* bcursor = bbase + 132;
    int* rows    = bcursor + 128;
    int* bpart   = rows + E;

    // ---- CSR build + weight prep (no memset: bpart is non-atomic) ----
    const int PREP_BLOCKS = cdiv(128 * 64 + 64 * 64 + 48 * 192, 256);
    k_init<<<NBH + PREP_BLOCKS, 256, 0, stream>>>(ei, bpart, E, NBH,
                                                  Wego, Wconv, Wcls, WTin, WT1, WcatT);
    k_bscan<<<1, 1024, 0, stream>>>(bpart, NBH, bbase, bcursor, NB);
    k_passA<<<NBA, 256, 0, stream>>>(ei, bcursor, sta, E);
    k_passB<<<NB, 256, 0, stream>>>(sta, bbase, indptr, dis, rows, N, NB);

    // ---- input layer (fused cast, MFMA) ----
    k_in<<<cdiv(cdiv(N, 16), 4), 256, 0, stream>>>(x, WTin, dis, bego, hws1, hall, N);

    // ---- hop 1: gather -> h1 (hall slice 1); hws2 = dis*(h1@Wconv1) ----
    k_gather<<<cdiv(N, 32), 256, 0, stream>>>(indptr, rows, dis, bconv,
                                              hws1, hall + 64, N);
    k_next1<<<cdiv(cdiv(N, 16), 4), 256, 0, stream>>>(hall, WT1, dis, hws2, N);

    // ---- hop 2: gather -> h2 (hall slice 2) ----
    k_gather<<<cdiv(N, 32), 256, 0, stream>>>(indptr, rows, dis, bconv + 64,
                                              hws2, hall + 128, N);

    // ---- classifier: out = bcls + hall @ Wcls (single pass) ----
    k_clsall<<<cdiv(cdiv(N, 16), 4), 256, 0, stream>>>(hall, WcatT, bcls, out, N);
}